// Round 3
// baseline (1005.341 us; speedup 1.0000x reference)
//
#include <hip/hip_runtime.h>
#include <hip/hip_bf16.h>
#include <cstdint>

// Problem constants
#define SDIM   2048
#define DDIM   1024
#define VDIM   50257
#define VPAD   50304          // 393 * 128
#define NROWS  4094           // B*(S-1) = 2*2047
#define MPAD   4096
#define NTM    32             // M tiles of 128
#define NTN    393            // N tiles of 128
#define NCHUNK (NTN * 2)      // 786 column chunks of 64
#define IGNORE_IDX (-100)

typedef __bf16 bf16x8 __attribute__((ext_vector_type(8)));
typedef float  f32x4  __attribute__((ext_vector_type(4)));

__device__ static inline unsigned short f2bf(float f) {
    union { float f; uint32_t u; } v; v.f = f;
    uint32_t u = v.u;
    return (unsigned short)((u + 0x7FFFu + ((u >> 16) & 1u)) >> 16);  // RNE
}

// global -> LDS direct (16B per lane). LDS dest is wave-uniform base + lane*16.
// NOTE: address-space casts must be C-style (static_cast rejects AS changes).
__device__ static inline void gload_lds16(const void* g, void* l) {
    __builtin_amdgcn_global_load_lds(
        (const __attribute__((address_space(1))) unsigned int*)(g),
        (__attribute__((address_space(3))) unsigned int*)(l),
        16, 0, 0);
}

// ---------------- convert W (fp32 [V,D]) -> bf16 [VPAD,D], pad rows zero ----
__global__ __launch_bounds__(256) void k_convert_W(const float* __restrict__ W,
                                                   unsigned short* __restrict__ Wb,
                                                   float* __restrict__ acc) {
    if (blockIdx.x == 0 && threadIdx.x < 2) acc[threadIdx.x] = 0.f;  // zero accumulators
    const int row = blockIdx.x;            // grid = VPAD
    const int c4  = threadIdx.x << 2;      // 256 threads * 4 = 1024 = D
    ushort4 o;
    if (row < VDIM) {
        const float4 f = *(const float4*)(W + (size_t)row * DDIM + c4);
        o.x = f2bf(f.x); o.y = f2bf(f.y); o.z = f2bf(f.z); o.w = f2bf(f.w);
    } else {
        o.x = o.y = o.z = o.w = 0;
    }
    *(ushort4*)(Wb + (size_t)row * DDIM + c4) = o;
}

// --------- pack shifted embeddings: row r<4094 -> emb[b= r/2047, s= r%2047] ---
__global__ __launch_bounds__(256) void k_convert_A(const float* __restrict__ emb,
                                                   unsigned short* __restrict__ Ab) {
    const int row = blockIdx.x;            // grid = MPAD
    const int c4  = threadIdx.x << 2;
    ushort4 o; o.x = o.y = o.z = o.w = 0;
    if (row < NROWS) {
        const int bb = row / 2047;
        const int s  = row - bb * 2047;
        const float4 f = *(const float4*)(emb + ((size_t)bb * SDIM + s) * DDIM + c4);
        o.x = f2bf(f.x); o.y = f2bf(f.y); o.z = f2bf(f.z); o.w = f2bf(f.w);
    }
    *(ushort4*)(Ab + (size_t)row * DDIM + c4) = o;
}

// ---------------- GEMM 128x128 tile + fused partial-logsumexp epilogue ------
// A: [MPAD][1024] bf16 row-major. B: [VPAD][1024] bf16 row-major (= logits^T rows).
// Per block: C tile [128 rows][128 cols]; 4 waves in 2x2, each 64x64.
// Epilogue: per row, per 64-col wave chunk -> (max, sum exp) partial.
__global__ __launch_bounds__(256) void k_gemm(const unsigned short* __restrict__ Ab,
                                              const unsigned short* __restrict__ Wb,
                                              const float* __restrict__ bias,
                                              float2* __restrict__ Pml) {
    __shared__ unsigned short As[128 * 32];   // 8 KB
    __shared__ unsigned short Bs[128 * 32];   // 8 KB

    const int tid  = threadIdx.x;
    const int wave = tid >> 6, lane = tid & 63;
    const int q    = lane & 15, g = lane >> 4;
    const int wr   = wave >> 1, wc = wave & 1;
    const int bid  = blockIdx.x;
    const int tm   = bid & 31;          // M fastest: consecutive blocks share W tile
    const int tn   = bid >> 5;
    const size_t arow0 = (size_t)tm * 128;
    const size_t brow0 = (size_t)tn * 128;

    f32x4 acc[4][4];
    const f32x4 zf = {0.f, 0.f, 0.f, 0.f};
#pragma unroll
    for (int i = 0; i < 4; ++i)
#pragma unroll
        for (int j = 0; j < 4; ++j) acc[i][j] = zf;

#pragma unroll 1
    for (int kt = 0; kt < DDIM / 32; ++kt) {
        const int kbase = kt * 32;
        // stage A and B tiles: per wave 2 issues each (64 lanes * 16B = 1KB per issue)
#pragma unroll
        for (int j = 0; j < 2; ++j) {
            const int ci  = j * 256 + tid;       // 16B chunk id within the 8KB tile
            const int row = ci >> 2;
            const int k8  = (ci & 3) * 8;
            gload_lds16(Ab + (arow0 + row) * DDIM + kbase + k8, &As[(j * 4 + wave) * 512]);
            gload_lds16(Wb + (brow0 + row) * DDIM + kbase + k8, &Bs[(j * 4 + wave) * 512]);
        }
        __syncthreads();   // vmcnt(0) drain: tile ready
        bf16x8 af[4], bf[4];
#pragma unroll
        for (int mi = 0; mi < 4; ++mi)
            af[mi] = *(const bf16x8*)(As + (wr * 64 + mi * 16 + q) * 32 + g * 8);
#pragma unroll
        for (int ni = 0; ni < 4; ++ni)
            bf[ni] = *(const bf16x8*)(Bs + (wc * 64 + ni * 16 + q) * 32 + g * 8);
        __syncthreads();   // ds_reads drained: LDS reusable next iter
#pragma unroll
        for (int mi = 0; mi < 4; ++mi)
#pragma unroll
            for (int ni = 0; ni < 4; ++ni)
                acc[mi][ni] = __builtin_amdgcn_mfma_f32_16x16x32_bf16(af[mi], bf[ni],
                                                                      acc[mi][ni], 0, 0, 0);
    }

    // -------- epilogue: per-row partial (max, sumexp) over this wave's 64 cols
    const float NEG_INF = -__builtin_inff();
    float bv[4]; int colv[4];
#pragma unroll
    for (int ni = 0; ni < 4; ++ni) {
        const int col = (int)brow0 + wc * 64 + ni * 16 + q;
        colv[ni] = col;
        bv[ni] = (col < VDIM) ? bias[col] : 0.f;
    }
#pragma unroll
    for (int mi = 0; mi < 4; ++mi) {
#pragma unroll
        for (int r = 0; r < 4; ++r) {
            float vv[4];
#pragma unroll
            for (int ni = 0; ni < 4; ++ni) {
                const float lv = acc[mi][ni][r] + bv[ni];
                vv[ni] = (colv[ni] < VDIM) ? lv : NEG_INF;
            }
            float m = fmaxf(fmaxf(vv[0], vv[1]), fmaxf(vv[2], vv[3]));
#pragma unroll
            for (int mask = 1; mask < 16; mask <<= 1) m = fmaxf(m, __shfl_xor(m, mask));
            float s = __expf(vv[0] - m) + __expf(vv[1] - m) +
                      __expf(vv[2] - m) + __expf(vv[3] - m);
#pragma unroll
            for (int mask = 1; mask < 16; mask <<= 1) s += __shfl_xor(s, mask);
            if (q == mi * 4 + r) {
                const int rowg = tm * 128 + wr * 64 + mi * 16 + g * 4 + r;
                Pml[(size_t)rowg * NCHUNK + (tn * 2 + wc)] = make_float2(m, s);
            }
        }
    }
}

// ---------------- finalize: per row, combine partials + label logit ---------
__global__ __launch_bounds__(256) void k_finalize(const float2* __restrict__ Pml,
                                                  const float* __restrict__ emb,
                                                  const float* __restrict__ W,
                                                  const float* __restrict__ bias,
                                                  const int* __restrict__ labels,
                                                  float* __restrict__ acc) {
    const int r    = blockIdx.x;          // 0..NROWS-1
    const int tid  = threadIdx.x;
    const int lane = tid & 63, wave = tid >> 6;
    const float NEG_INF = -__builtin_inff();

    float m = NEG_INF, l = 0.f;
    for (int c = tid; c < NCHUNK; c += 256) {
        const float2 p = Pml[(size_t)r * NCHUNK + c];
        const float mn = fmaxf(m, p.x);
        l = l * __expf(m - mn) + p.y * __expf(p.x - mn);
        m = mn;
    }
#pragma unroll
    for (int mask = 1; mask < 64; mask <<= 1) {
        const float om = __shfl_xor(m, mask);
        const float ol = __shfl_xor(l, mask);
        const float mn = fmaxf(m, om);
        l = l * __expf(m - mn) + ol * __expf(om - mn);
        m = mn;
    }

    // label logit: fp32 dot(emb_row, W[label]) + bias[label]
    const int bb = r / 2047;
    const int s  = r - bb * 2047;
    const int label = labels[bb * SDIM + s + 1];
    const bool valid = (label != IGNORE_IDX);
    const int lab = valid ? label : 0;
    const float* erow = emb + ((size_t)bb * SDIM + s) * DDIM;
    const float* wrow = W + (size_t)lab * DDIM;
    const float4 e  = *(const float4*)(erow + tid * 4);
    const float4 w4 = *(const float4*)(wrow + tid * 4);
    float d = e.x * w4.x + e.y * w4.y + e.z * w4.z + e.w * w4.w;
#pragma unroll
    for (int mask = 1; mask < 64; mask <<= 1) d += __shfl_xor(d, mask);

    __shared__ float sm[4], sl[4], sd[4];
    if (lane == 0) { sm[wave] = m; sl[wave] = l; sd[wave] = d; }
    __syncthreads();
    if (tid == 0) {
        float M = sm[0], L = sl[0];
#pragma unroll
        for (int wv = 1; wv < 4; ++wv) {
            const float mn = fmaxf(M, sm[wv]);
            L = L * __expf(M - mn) + sl[wv] * __expf(sm[wv] - mn);
            M = mn;
        }
        const float dot = sd[0] + sd[1] + sd[2] + sd[3];
        const float lse = M + logf(L);
        const float logit = dot + bias[lab];
        const float ce = valid ? (lse - logit) : 0.f;
        const float pt = __expf(-ce);
        const float w  = valid ? (1.f - pt) : 0.f;   // gamma = 1.0
        atomicAdd(acc + 0, w * ce);
        atomicAdd(acc + 1, w);
    }
}

__global__ void k_final(const float* __restrict__ acc, float* __restrict__ out) {
    out[0] = acc[0] / acc[1];
}

extern "C" void kernel_launch(void* const* d_in, const int* in_sizes, int n_in,
                              void* d_out, int out_size, void* d_ws, size_t ws_size,
                              hipStream_t stream) {
    const float* emb    = (const float*)d_in[0];
    const float* W      = (const float*)d_in[1];
    const float* bias   = (const float*)d_in[2];
    const int*   labels = (const int*)d_in[3];
    // d_in[4] (input_ids) unused

    char* ws = (char*)d_ws;
    const size_t WB = (size_t)VPAD * DDIM * 2;       // 103,022,592
    const size_t AB = (size_t)MPAD * DDIM * 2;       //   8,388,608
    const size_t PB = (size_t)MPAD * NCHUNK * 8;     //  25,755,648
    unsigned short* Wb  = (unsigned short*)ws;
    unsigned short* Ab  = (unsigned short*)(ws + WB);
    float2*         Pml = (float2*)(ws + WB + AB);
    float*          acc = (float*)(ws + WB + AB + PB);

    k_convert_W<<<VPAD, 256, 0, stream>>>(W, Wb, acc);
    k_convert_A<<<MPAD, 256, 0, stream>>>(emb, Ab);
    k_gemm<<<NTM * NTN, 256, 0, stream>>>(Ab, Wb, bias, Pml);
    k_finalize<<<NROWS, 256, 0, stream>>>(Pml, emb, W, bias, labels, acc);
    k_final<<<1, 1, 0, stream>>>(acc, (float*)d_out);
}

// Round 5
// 909.770 us; speedup vs baseline: 1.1050x; 1.1050x over previous
//
#include <hip/hip_runtime.h>
#include <hip/hip_bf16.h>
#include <cstdint>

// Problem constants
#define SDIM   2048
#define DDIM   1024
#define VDIM   50257
#define VPAD   50432          // 197 * 256
#define NROWS  4094           // B*(S-1) = 2*2047
#define MPAD   4096
#define NTM    16             // M tiles of 256
#define NTN    197            // N tiles of 256
#define NCHUNK (NTN * 4)      // 788 column chunks of 64
#define NKT    16             // 1024 / 64
#define IGNORE_IDX (-100)
// Finite "minus infinity": avoids exp(-inf - -inf) = NaN on all-padding chunks.
#define NEGBIG (-3.0e38f)

typedef __bf16 bf16x8 __attribute__((ext_vector_type(8)));
typedef float  f32x4  __attribute__((ext_vector_type(4)));

__device__ static inline unsigned short f2bf(float f) {
    union { float f; uint32_t u; } v; v.f = f;
    uint32_t u = v.u;
    return (unsigned short)((u + 0x7FFFu + ((u >> 16) & 1u)) >> 16);  // RNE
}

// global -> LDS direct (16B per lane). LDS dest must be wave-uniform base + lane*16.
__device__ static inline void gload_lds16(const void* g, void* l) {
    __builtin_amdgcn_global_load_lds(
        (const __attribute__((address_space(1))) unsigned int*)(g),
        (__attribute__((address_space(3))) unsigned int*)(l),
        16, 0, 0);
}

// ---------------- convert W (fp32 [V,D]) -> bf16 [VPAD,D], pad rows zero ----
__global__ __launch_bounds__(256) void k_convert_W(const float* __restrict__ W,
                                                   unsigned short* __restrict__ Wb,
                                                   float* __restrict__ acc) {
    if (blockIdx.x == 0 && threadIdx.x < 2) acc[threadIdx.x] = 0.f;  // zero accumulators
    const int row = blockIdx.x;            // grid = VPAD
    const int c4  = threadIdx.x << 2;      // 256 threads * 4 = 1024 = D
    ushort4 o;
    if (row < VDIM) {
        const float4 f = *(const float4*)(W + (size_t)row * DDIM + c4);
        o.x = f2bf(f.x); o.y = f2bf(f.y); o.z = f2bf(f.z); o.w = f2bf(f.w);
    } else {
        o.x = o.y = o.z = o.w = 0;
    }
    *(ushort4*)(Wb + (size_t)row * DDIM + c4) = o;
}

// --------- pack shifted embeddings: row r<4094 -> emb[b= r/2047, s= r%2047] ---
__global__ __launch_bounds__(256) void k_convert_A(const float* __restrict__ emb,
                                                   unsigned short* __restrict__ Ab) {
    const int row = blockIdx.x;            // grid = MPAD
    const int c4  = threadIdx.x << 2;
    ushort4 o; o.x = o.y = o.z = o.w = 0;
    if (row < NROWS) {
        const int bb = row / 2047;
        const int s  = row - bb * 2047;
        const float4 f = *(const float4*)(emb + ((size_t)bb * SDIM + s) * DDIM + c4);
        o.x = f2bf(f.x); o.y = f2bf(f.y); o.z = f2bf(f.z); o.w = f2bf(f.w);
    }
    *(ushort4*)(Ab + (size_t)row * DDIM + c4) = o;
}

// ---------------- GEMM 256x256 tile, BK=64, 8 waves, phased pipeline --------
// LDS per matrix per buf: [256 rows][64 cols] bf16 (128B rows), slot-swizzled:
// element (row,col) lives at byte row*128 + (((col>>3) ^ (row&7))<<4) + (col&7)*2.
// global_load_lds writes linearly (wave-uniform base + lane*16); the global
// SOURCE is pre-swizzled with the same XOR involution (rule 21). Reads apply
// the XOR.
__global__ __launch_bounds__(512, 2) void k_gemm(const unsigned short* __restrict__ Ab,
                                                 const unsigned short* __restrict__ Wb,
                                                 const float* __restrict__ bias,
                                                 float2* __restrict__ Pml) {
    extern __shared__ unsigned short lds[];        // 128 KiB dynamic
    unsigned short* As = lds;                      // [2][256*64]
    unsigned short* Bs = lds + 2 * 256 * 64;       // [2][256*64]

    const int tid  = threadIdx.x;
    const int wave = tid >> 6, lane = tid & 63;
    const int q    = lane & 15, g = lane >> 4;
    const int wr   = wave >> 2;        // 0..1  (M half: 128 rows)
    const int wc   = wave & 3;         // 0..3  (N quarter: 64 cols)

    // Bijective XCD swizzle: nwg = 16*197 = 3152, 3152 % 8 == 0.
    const int bid0 = (int)blockIdx.x;
    const int bid  = (bid0 & 7) * (NTM * NTN / 8) + (bid0 >> 3);
    const int tm   = bid & 15;         // M fastest: consecutive blocks share W panel
    const int tn   = bid >> 4;
    const size_t arow0 = (size_t)tm * 256;
    const size_t brow0 = (size_t)tn * 256;

    f32x4 acc[8][4];
    const f32x4 zf = {0.f, 0.f, 0.f, 0.f};
#pragma unroll
    for (int i = 0; i < 8; ++i)
#pragma unroll
        for (int j = 0; j < 4; ++j) acc[i][j] = zf;

    // stage one (matrix, row-half) unit = 128 rows x 64 cols = 16KB = 2 loads/lane.
    // LDS base passed wave-uniform; lane l lands at base + l*16 = chunk ci = j*512+tid.
    auto stage_unit = [&](const unsigned short* G, size_t grow0, int kt, int h,
                          unsigned short* L) {
#pragma unroll
        for (int j = 0; j < 2; ++j) {
            const int ci   = j * 512 + tid;          // this lane's 16B chunk id
            const int row  = h * 128 + (ci >> 3);
            const int slot = ci & 7;
            const int ss   = slot ^ (row & 7);       // pre-swizzled source slot
            gload_lds16(G + (grow0 + row) * DDIM + kt * 64 + ss * 8,
                        L + h * (128 * 64) + (size_t)(j * 512 + wave * 64) * 8);
        }
    };

    auto phase = [&](int c, int mh, int ks, bool stA, bool stB, int ktn, bool do_vm) {
        const unsigned short* Ac = As + c * (256 * 64);
        const unsigned short* Bc = Bs + c * (256 * 64);
        bf16x8 af[4], bfr[4];
#pragma unroll
        for (int fi = 0; fi < 4; ++fi) {
            const int row = wr * 128 + mh * 64 + fi * 16 + q;
            const int sl  = (ks * 4 + g) ^ (row & 7);
            af[fi] = *(const bf16x8*)(Ac + row * 64 + sl * 8);
        }
#pragma unroll
        for (int fj = 0; fj < 4; ++fj) {
            const int row = wc * 64 + fj * 16 + q;
            const int sl  = (ks * 4 + g) ^ (row & 7);
            bfr[fj] = *(const bf16x8*)(Bc + row * 64 + sl * 8);
        }
        if (stA) {
            stage_unit(Ab, arow0, ktn, 0, As + (c ^ 1) * (256 * 64));
            stage_unit(Ab, arow0, ktn, 1, As + (c ^ 1) * (256 * 64));
        }
        if (stB) {
            stage_unit(Wb, brow0, ktn, 0, Bs + (c ^ 1) * (256 * 64));
            stage_unit(Wb, brow0, ktn, 1, Bs + (c ^ 1) * (256 * 64));
        }
        if (do_vm) asm volatile("s_waitcnt vmcnt(0)" ::: "memory");
        __builtin_amdgcn_sched_barrier(0);
        __builtin_amdgcn_s_barrier();
        asm volatile("s_waitcnt lgkmcnt(0)" ::: "memory");
        __builtin_amdgcn_sched_barrier(0);
        __builtin_amdgcn_s_setprio(1);
#pragma unroll
        for (int fi = 0; fi < 4; ++fi)
#pragma unroll
            for (int fj = 0; fj < 4; ++fj)
                acc[mh * 4 + fi][fj] = __builtin_amdgcn_mfma_f32_16x16x32_bf16(
                    af[fi], bfr[fj], acc[mh * 4 + fi][fj], 0, 0, 0);
        __builtin_amdgcn_s_setprio(0);
        __builtin_amdgcn_sched_barrier(0);
    };

    // prologue: stage tile 0 into buf 0, drain, barrier
    stage_unit(Ab, arow0, 0, 0, As);
    stage_unit(Ab, arow0, 0, 1, As);
    stage_unit(Wb, brow0, 0, 0, Bs);
    stage_unit(Wb, brow0, 0, 1, Bs);
    asm volatile("s_waitcnt vmcnt(0)" ::: "memory");
    __builtin_amdgcn_sched_barrier(0);
    __builtin_amdgcn_s_barrier();

#pragma unroll 1
    for (int t = 0; t < NKT; ++t) {
        const int  c  = t & 1;
        const bool st = (t < NKT - 1);
        phase(c, 0, 0, st, false, t + 1, false);   // stage A halves of t+1
        phase(c, 0, 1, false, st, t + 1, false);   // stage B halves of t+1
        phase(c, 1, 0, false, false, t + 1, false);
        phase(c, 1, 1, false, false, t + 1, true); // vmcnt(0): t+1 fully landed
    }

    // -------- epilogue: per-row partial (max, sumexp) over this wave's 64 cols
    float bv[4]; int colv[4];
#pragma unroll
    for (int fj = 0; fj < 4; ++fj) {
        const int col = tn * 256 + wc * 64 + fj * 16 + q;
        colv[fj] = col;
        bv[fj] = (col < VDIM) ? bias[col] : 0.f;
    }
#pragma unroll
    for (int mf = 0; mf < 8; ++mf) {
#pragma unroll
        for (int r = 0; r < 4; ++r) {
            float vv[4];
#pragma unroll
            for (int fj = 0; fj < 4; ++fj) {
                const float lv = acc[mf][fj][r] + bv[fj];
                vv[fj] = (colv[fj] < VDIM) ? lv : NEGBIG;
            }
            float m = fmaxf(fmaxf(vv[0], vv[1]), fmaxf(vv[2], vv[3]));
#pragma unroll
            for (int mask = 1; mask < 16; mask <<= 1) m = fmaxf(m, __shfl_xor(m, mask));
            // all-pad chunk: m == NEGBIG, vv-m == 0, s harmless (zeroed in combine)
            float s = __expf(vv[0] - m) + __expf(vv[1] - m) +
                      __expf(vv[2] - m) + __expf(vv[3] - m);
#pragma unroll
            for (int mask = 1; mask < 16; mask <<= 1) s += __shfl_xor(s, mask);
            if (q == ((mf * 4 + r) & 15)) {
                const int rowg = tm * 256 + wr * 128 + mf * 16 + g * 4 + r;
                Pml[(size_t)rowg * NCHUNK + (tn * 4 + wc)] = make_float2(m, s);
            }
        }
    }
}

// ---------------- finalize: per row, combine partials + label logit ---------
__global__ __launch_bounds__(256) void k_finalize(const float2* __restrict__ Pml,
                                                  const float* __restrict__ emb,
                                                  const float* __restrict__ W,
                                                  const float* __restrict__ bias,
                                                  const int* __restrict__ labels,
                                                  float* __restrict__ acc) {
    const int r    = blockIdx.x;          // 0..NROWS-1
    const int tid  = threadIdx.x;
    const int lane = tid & 63, wave = tid >> 6;

    float m = NEGBIG, l = 0.f;
    for (int c = tid; c < NCHUNK; c += 256) {
        const float2 p = Pml[(size_t)r * NCHUNK + c];
        const float mn = fmaxf(m, p.x);
        l = l * __expf(m - mn) + p.y * __expf(p.x - mn);
        m = mn;
    }
#pragma unroll
    for (int mask = 1; mask < 64; mask <<= 1) {
        const float om = __shfl_xor(m, mask);
        const float ol = __shfl_xor(l, mask);
        const float mn = fmaxf(m, om);
        l = l * __expf(m - mn) + ol * __expf(om - mn);
        m = mn;
    }

    // label logit: fp32 dot(emb_row, W[label]) + bias[label]
    const int bb = r / 2047;
    const int s  = r - bb * 2047;
    const int label = labels[bb * SDIM + s + 1];
    const bool valid = (label != IGNORE_IDX);
    const int lab = valid ? label : 0;
    const float* erow = emb + ((size_t)bb * SDIM + s) * DDIM;
    const float* wrow = W + (size_t)lab * DDIM;
    const float4 e  = *(const float4*)(erow + tid * 4);
    const float4 w4 = *(const float4*)(wrow + tid * 4);
    float d = e.x * w4.x + e.y * w4.y + e.z * w4.z + e.w * w4.w;
#pragma unroll
    for (int mask = 1; mask < 64; mask <<= 1) d += __shfl_xor(d, mask);

    __shared__ float sm[4], sl[4], sd[4];
    if (lane == 0) { sm[wave] = m; sl[wave] = l; sd[wave] = d; }
    __syncthreads();
    if (tid == 0) {
        float M = sm[0], L = sl[0];
#pragma unroll
        for (int wv = 1; wv < 4; ++wv) {
            const float mn = fmaxf(M, sm[wv]);
            L = L * __expf(M - mn) + sl[wv] * __expf(sm[wv] - mn);
            M = mn;
        }
        const float dot = sd[0] + sd[1] + sd[2] + sd[3];
        const float lse = M + logf(L);
        const float logit = dot + bias[lab];
        const float ce = valid ? (lse - logit) : 0.f;
        const float pt = __expf(-ce);
        const float w  = valid ? (1.f - pt) : 0.f;   // gamma = 1.0
        atomicAdd(acc + 0, w * ce);
        atomicAdd(acc + 1, w);
    }
}

__global__ void k_final(const float* __restrict__ acc, float* __restrict__ out) {
    out[0] = acc[0] / acc[1];
}

extern "C" void kernel_launch(void* const* d_in, const int* in_sizes, int n_in,
                              void* d_out, int out_size, void* d_ws, size_t ws_size,
                              hipStream_t stream) {
    const float* emb    = (const float*)d_in[0];
    const float* W      = (const float*)d_in[1];
    const float* bias   = (const float*)d_in[2];
    const int*   labels = (const int*)d_in[3];
    // d_in[4] (input_ids) unused

    char* ws = (char*)d_ws;
    const size_t WB = (size_t)VPAD * DDIM * 2;       // 103,284,736
    const size_t AB = (size_t)MPAD * DDIM * 2;       //   8,388,608
    const size_t PB = (size_t)MPAD * NCHUNK * 8;     //  25,821,184
    unsigned short* Wb  = (unsigned short*)ws;
    unsigned short* Ab  = (unsigned short*)(ws + WB);
    float2*         Pml = (float2*)(ws + WB + AB);
    float*          acc = (float*)(ws + WB + AB + PB);

    k_convert_W<<<VPAD, 256, 0, stream>>>(W, Wb, acc);
    k_convert_A<<<MPAD, 256, 0, stream>>>(emb, Ab);
    k_gemm<<<NTM * NTN, 512, 131072, stream>>>(Ab, Wb, bias, Pml);
    k_finalize<<<NROWS, 256, 0, stream>>>(Pml, emb, W, bias, labels, acc);
    k_final<<<1, 1, 0, stream>>>(acc, (float*)d_out);
}